// Round 7
// baseline (273.617 us; speedup 1.0000x reference)
//
#include <hip/hip_runtime.h>

typedef __bf16 bf16x8 __attribute__((ext_vector_type(8)));
typedef float f32x4 __attribute__((ext_vector_type(4)));
typedef unsigned short ushort8v __attribute__((ext_vector_type(8)));
typedef unsigned short ushort4v __attribute__((ext_vector_type(4)));

#define BATCH 32
#define NBOX 40
#define CCH 256
#define HF 64
#define WF 64
#define RREG 29
#define OUTP 7
#define MROWS 928           // BATCH*RREG
#define DDIM 12544          // CCH*7*7
#define N1DIM 2048
#define FDIM 768
#define PDIM 4096           // HF*WF
#define S1 8                // split-K factor GEMM1
#define S2 8                // split-K factor GEMM2

// ---- workspace layout (bytes), lifetime-aliased ----
static constexpr size_t OFF_ROIS = 0;                                   // 928*4 f32
static constexpr size_t OFF_DET  = 16384;                               // 928 i32
static constexpr size_t OFF_A    = 32768;                               // bf16 [928][12544]
static constexpr size_t OFF_W1T  = OFF_A   + (size_t)MROWS * DDIM * 2;  // bf16 [2048][12544]
static constexpr size_t OFF_W2T  = OFF_W1T + (size_t)DDIM * N1DIM * 2;  // bf16 [768][2048]
static constexpr size_t OFF_GP   = OFF_W2T + (size_t)N1DIM * FDIM * 2;  // f32 [S1][928][2048]; later [S2][928][768]
static constexpr size_t OFF_H    = OFF_W1T;                             // bf16 [928][2048] (W1T dead after gemm1)

static __device__ __forceinline__ unsigned short f2bf(float f) {
  __bf16 h = (__bf16)f;
  return __builtin_bit_cast(unsigned short, h);
}
static __device__ __forceinline__ float bf2f(unsigned short u) {
  unsigned int x = ((unsigned int)u) << 16;
  return __builtin_bit_cast(float, x);
}
static __device__ __forceinline__ void gload_lds16(const void* g, void* l) {
  __builtin_amdgcn_global_load_lds((const __attribute__((address_space(1))) void*)g,
                                   (__attribute__((address_space(3))) void*)l, 16, 0, 0);
}

// ---------------- 1. box selection ----------------
__global__ __launch_bounds__(256) void select_kernel(const float* __restrict__ boxes,
                                                     const float* __restrict__ scores,
                                                     const int* __restrict__ labels,
                                                     float* __restrict__ rois,
                                                     int* __restrict__ det,
                                                     float* __restrict__ out_det) {
  int tid = blockIdx.x * 256 + threadIdx.x;
  if (tid >= MROWS) return;
  int b = tid / RREG, r = tid % RREG;
  float bestS = -1.0f;
  int bestN = 0;
  int found = 0;
  for (int n = 0; n < NBOX; ++n) {
    int lab = labels[b * NBOX + n];
    int ri = min(max(lab, 1), RREG) - 1;
    if (ri == r) {
      found = 1;
      float s = scores[b * NBOX + n];
      if (s > bestS) { bestS = s; bestN = n; }
    }
  }
  const float scale = 0.0625f;
  float4 bx = *(const float4*)&boxes[(b * NBOX + bestN) * 4];
  rois[tid * 4 + 0] = bx.x * scale;
  rois[tid * 4 + 1] = bx.y * scale;
  rois[tid * 4 + 2] = bx.z * scale;
  rois[tid * 4 + 3] = bx.w * scale;
  det[tid] = found;
  out_det[tid] = found ? 1.0f : 0.0f;
}

// ---------------- 2. fused roi-align from native NCHW f32 -> bf16 A [928][12544] ----
// block = (batch b, channel-group cg of 8). Stages 8 fm planes as bf16 in LDS
// (padded stride kills the 8 KiB same-bank alias), then per roi: 196-thread
// sample table (computed once per block, not per channel), 392 (ch,bin)
// outputs read 16 LDS taps each and write contiguous bf16.
__global__ __launch_bounds__(256) void roialign_kernel(const float* __restrict__ fm,
                                                       const float* __restrict__ rois,
                                                       unsigned short* __restrict__ A) {
  __shared__ unsigned short planes[8][4104];   // +8 pad
  __shared__ int4 sidx[196];
  __shared__ float4 swt[196];
  int b = blockIdx.x;
  int cg = blockIdx.y;
  int t = threadIdx.x;

  const float4* src = (const float4*)(fm + ((long)b * CCH + cg * 8) * PDIM);
  for (int i = t; i < 8192; i += 256) {        // 8 planes x 1024 float4
    int pl = i >> 10, off = (i & 1023) * 4;
    float4 v = src[i];
    ushort4v o = {f2bf(v.x), f2bf(v.y), f2bf(v.z), f2bf(v.w)};
    *(ushort4v*)&planes[pl][off] = o;
  }

  for (int r = 0; r < RREG; ++r) {
    __syncthreads();   // planes ready (r=0) / prev-roi readers done (r>0)
    int roi = b * RREG + r;
    if (t < 196) {
      float rx1 = rois[roi * 4 + 0], ry1 = rois[roi * 4 + 1];
      float rx2 = rois[roi * 4 + 2], ry2 = rois[roi * 4 + 3];
      float roiw = fmaxf(rx2 - rx1, 1.f), roih = fmaxf(ry2 - ry1, 1.f);
      float bw = roiw * (1.f / OUTP), bh = roih * (1.f / OUTP);
      int oy = t / 28, rem = t % 28, ox = rem / 4, s = rem % 4, sy = s >> 1, sx = s & 1;
      float y = ry1 + ((float)oy + ((float)sy + 0.5f) * 0.5f) * bh;
      float x = rx1 + ((float)ox + ((float)sx + 0.5f) * 0.5f) * bw;
      bool valid = (y >= -1.f) && (y <= 64.f) && (x >= -1.f) && (x <= 64.f);
      float yc = fminf(fmaxf(y, 0.f), 63.f);
      float xc = fminf(fmaxf(x, 0.f), 63.f);
      int y0 = (int)floorf(yc), x0 = (int)floorf(xc);
      int y1i = min(y0 + 1, 63), x1i = min(x0 + 1, 63);
      float ly = yc - (float)y0, lx = xc - (float)x0;
      float hy = 1.f - ly, hx = 1.f - lx;
      float m = valid ? 1.f : 0.f;
      swt[t] = make_float4(hy * hx * m, hy * lx * m, ly * hx * m, ly * lx * m);
      sidx[t] = make_int4(y0 * 64 + x0, y0 * 64 + x1i, y1i * 64 + x0, y1i * 64 + x1i);
    }
    __syncthreads();
    long abase = (long)roi * DDIM + (long)cg * 8 * 49;
    for (int idx = t; idx < 392; idx += 256) {   // idx = cl*49 + bin
      int cl = idx / 49, bin = idx - cl * 49;
      float acc = 0.f;
#pragma unroll
      for (int s = 0; s < 4; ++s) {
        int sid = bin * 4 + s;
        int4 ix = sidx[sid];
        float4 w = swt[sid];
        acc += w.x * bf2f(planes[cl][ix.x]) + w.y * bf2f(planes[cl][ix.y])
             + w.z * bf2f(planes[cl][ix.z]) + w.w * bf2f(planes[cl][ix.w]);
      }
      A[abase + idx] = f2bf(acc * 0.25f);
    }
  }
}

// ---------------- 3. merged transpose f32 [K][N] -> bf16 [N][K] for w1 and w2 ------
__global__ __launch_bounds__(256) void wT_kernel(const float* __restrict__ w1,
                                                 unsigned short* __restrict__ w1t,
                                                 const float* __restrict__ w2,
                                                 unsigned short* __restrict__ w2t) {
  __shared__ float tile[64][65];
  int bid = blockIdx.x;
  const float* in;
  unsigned short* out;
  int K, N, k0, n0;
  if (bid < (DDIM / 64) * (N1DIM / 64)) {
    in = w1; out = w1t; K = DDIM; N = N1DIM;
    k0 = (bid % (DDIM / 64)) * 64;
    n0 = (bid / (DDIM / 64)) * 64;
  } else {
    int r = bid - (DDIM / 64) * (N1DIM / 64);
    in = w2; out = w2t; K = N1DIM; N = FDIM;
    k0 = (r % (N1DIM / 64)) * 64;
    n0 = (r / (N1DIM / 64)) * 64;
  }
  int t = threadIdx.x, tx = t & 15, ty = t >> 4;
#pragma unroll
  for (int p = 0; p < 4; ++p) {
    int r = ty + p * 16;
    float4 v = *(const float4*)&in[(long)(k0 + r) * N + n0 + tx * 4];
    tile[r][tx * 4 + 0] = v.x;
    tile[r][tx * 4 + 1] = v.y;
    tile[r][tx * 4 + 2] = v.z;
    tile[r][tx * 4 + 3] = v.w;
  }
  __syncthreads();
#pragma unroll
  for (int p = 0; p < 4; ++p) {
    int r = ty + p * 16;
    ushort4v o;
    o[0] = f2bf(tile[tx * 4 + 0][r]);
    o[1] = f2bf(tile[tx * 4 + 1][r]);
    o[2] = f2bf(tile[tx * 4 + 2][r]);
    o[3] = f2bf(tile[tx * 4 + 3][r]);
    *(ushort4v*)&out[(long)(n0 + r) * K + k0 + tx * 4] = o;
  }
}

// ---------------- 4. split-K bf16 MFMA GEMM, counted-vmcnt pipeline ----------
__global__ __launch_bounds__(256, 2) void gemm_sk_kernel(const unsigned short* __restrict__ A,
                                                         const unsigned short* __restrict__ Bt,
                                                         float* __restrict__ Cp,
                                                         int M, int N, int K, int kchunk,
                                                         int gy, int q) {
  __shared__ unsigned short As[2 * 128 * 64];   // [buf][row][chunk^(row&7)] bf16
  __shared__ unsigned short Bs[2 * 128 * 64];
  int bid = blockIdx.x;
  int tile = (bid & 7) * q + (bid >> 3);    // bijective XCD-chunked swizzle (nwg % 8 == 0)
  int bm = tile & 7;
  int rest = tile >> 3;
  int bn = rest % gy;
  int s = rest / gy;

  int t = threadIdx.x;
  int lane = t & 63, wv = t >> 6;
  int wr = wv >> 1, wc = wv & 1;
  int fr = lane & 15, fq = lane >> 4;

  f32x4 acc[4][4];
#pragma unroll
  for (int m = 0; m < 4; ++m)
#pragma unroll
    for (int n = 0; n < 4; ++n) acc[m][n] = (f32x4){0.f, 0.f, 0.f, 0.f};

  int srow = t >> 3;
  int scol = t & 7;
  int k_begin = s * kchunk;
  int k_end = min(k_begin + kchunk, K);
  int nkt = (k_end - k_begin) >> 6;

  int garow[4], gbrow[4], schunk[4];
#pragma unroll
  for (int i = 0; i < 4; ++i) {
    int row = srow + i * 32;
    schunk[i] = (scol ^ (row & 7)) * 8;
    garow[i] = min(bm * 128 + row, M - 1);
    gbrow[i] = bn * 128 + row;
  }

#define GSTAGE(buf, kt_) do {                                                  \
    int k0_ = k_begin + (kt_) * 64;                                            \
    _Pragma("unroll")                                                          \
    for (int i = 0; i < 4; ++i)                                                \
      gload_lds16(A + (long)garow[i] * K + k0_ + schunk[i],                    \
                  (char*)As + (buf) * 16384 + t * 16 + i * 4096);              \
    _Pragma("unroll")                                                          \
    for (int i = 0; i < 4; ++i)                                                \
      gload_lds16(Bt + (long)gbrow[i] * K + k0_ + schunk[i],                   \
                  (char*)Bs + (buf) * 16384 + t * 16 + i * 4096);              \
  } while (0)

  GSTAGE(0, 0);
  GSTAGE(1, min(1, nkt - 1));

  for (int kt = 0; kt < nkt; ++kt) {
    int cur = kt & 1;
    asm volatile("s_waitcnt vmcnt(8)" ::: "memory");
    __builtin_amdgcn_sched_barrier(0);
    __builtin_amdgcn_s_barrier();
    __builtin_amdgcn_sched_barrier(0);

    const char* Ab = (const char*)As + cur * 16384;
    const char* Bb = (const char*)Bs + cur * 16384;
#pragma unroll
    for (int ks = 0; ks < 2; ++ks) {
      bf16x8 af[4], bfv[4];
#pragma unroll
      for (int m = 0; m < 4; ++m) {
        int row = wr * 64 + m * 16 + fr;
        int bc = (ks * 64 + fq * 16) ^ ((row & 7) << 4);
        af[m] = *(const bf16x8*)(Ab + row * 128 + bc);
      }
#pragma unroll
      for (int n = 0; n < 4; ++n) {
        int row = wc * 64 + n * 16 + fr;
        int bc = (ks * 64 + fq * 16) ^ ((row & 7) << 4);
        bfv[n] = *(const bf16x8*)(Bb + row * 128 + bc);
      }
#pragma unroll
      for (int m = 0; m < 4; ++m)
#pragma unroll
        for (int n = 0; n < 4; ++n)
          acc[m][n] = __builtin_amdgcn_mfma_f32_16x16x32_bf16(af[m], bfv[n], acc[m][n], 0, 0, 0);
    }

    __builtin_amdgcn_sched_barrier(0);
    __builtin_amdgcn_s_barrier();
    __builtin_amdgcn_sched_barrier(0);
    GSTAGE(cur, min(kt + 2, nkt - 1));
  }
#undef GSTAGE

  float* Cb = Cp + (long)s * M * N;
#pragma unroll
  for (int m = 0; m < 4; ++m)
#pragma unroll
    for (int n = 0; n < 4; ++n) {
      int col = bn * 128 + wc * 64 + n * 16 + fr;
#pragma unroll
      for (int j = 0; j < 4; ++j) {
        int row = bm * 128 + wr * 64 + m * 16 + fq * 4 + j;
        if (row < M) Cb[(long)row * N + col] = acc[m][n][j];
      }
    }
}

// ---------------- block reduce helper ----------------
static __device__ __forceinline__ void block_reduce2(float& a, float& b, float* sm) {
#pragma unroll
  for (int off = 32; off > 0; off >>= 1) {
    a += __shfl_down(a, off);
    b += __shfl_down(b, off);
  }
  int lane = threadIdx.x & 63, wv = threadIdx.x >> 6;
  if (lane == 0) { sm[wv] = a; sm[wv + 4] = b; }
  __syncthreads();
  a = sm[0] + sm[1] + sm[2] + sm[3];
  b = sm[4] + sm[5] + sm[6] + sm[7];
}

// ---------------- 5. partial-sum + bias + LN + ReLU -> bf16 h ----------------
__global__ __launch_bounds__(256) void ln1_kernel(const float* __restrict__ X,
                                                  const float* __restrict__ b1,
                                                  const float* __restrict__ g1,
                                                  const float* __restrict__ be1,
                                                  unsigned short* __restrict__ H) {
  __shared__ float sm[8];
  int row = blockIdx.x, t = threadIdx.x;
  float x[8];
  float sum = 0.f, sq = 0.f;
#pragma unroll
  for (int i = 0; i < 8; ++i) {
    int j = t + i * 256;
    float v = b1[j];
#pragma unroll
    for (int s = 0; s < S1; ++s) v += X[((long)s * MROWS + row) * N1DIM + j];
    x[i] = v;
    sum += v;
    sq += v * v;
  }
  block_reduce2(sum, sq, sm);
  float mu = sum * (1.f / N1DIM);
  float inv = rsqrtf(sq * (1.f / N1DIM) - mu * mu + 1e-5f);
#pragma unroll
  for (int i = 0; i < 8; ++i) {
    int j = t + i * 256;
    float y = fmaxf((x[i] - mu) * inv * g1[j] + be1[j], 0.f);
    H[(long)row * N1DIM + j] = f2bf(y);
  }
}

// ---------------- 6. partial-sum + bias + LN + missing-token -> out ----------------
__global__ __launch_bounds__(256) void ln2_kernel(const float* __restrict__ X,
                                                  const float* __restrict__ b2,
                                                  const float* __restrict__ g2,
                                                  const float* __restrict__ be2,
                                                  const float* __restrict__ miss,
                                                  const int* __restrict__ det,
                                                  float* __restrict__ out) {
  __shared__ float sm[8];
  int row = blockIdx.x, t = threadIdx.x;
  float x[3];
  float sum = 0.f, sq = 0.f;
#pragma unroll
  for (int i = 0; i < 3; ++i) {
    int j = t + i * 256;
    float v = b2[j];
#pragma unroll
    for (int s = 0; s < S2; ++s) v += X[((long)s * MROWS + row) * FDIM + j];
    x[i] = v;
    sum += v;
    sq += v * v;
  }
  block_reduce2(sum, sq, sm);
  float mu = sum * (1.f / FDIM);
  float inv = rsqrtf(sq * (1.f / FDIM) - mu * mu + 1e-5f);
  int dv = det[row];
#pragma unroll
  for (int i = 0; i < 3; ++i) {
    int j = t + i * 256;
    float y = (x[i] - mu) * inv * g2[j] + be2[j];
    out[(long)row * FDIM + j] = dv ? y : miss[j];
  }
}

extern "C" void kernel_launch(void* const* d_in, const int* in_sizes, int n_in,
                              void* d_out, int out_size, void* d_ws, size_t ws_size,
                              hipStream_t stream) {
  const float* fm     = (const float*)d_in[0];
  const float* boxes  = (const float*)d_in[1];
  const float* scores = (const float*)d_in[2];
  const int*   labels = (const int*)d_in[3];
  const float* w1     = (const float*)d_in[4];
  const float* b1     = (const float*)d_in[5];
  const float* g1     = (const float*)d_in[6];
  const float* be1    = (const float*)d_in[7];
  const float* w2     = (const float*)d_in[8];
  const float* b2     = (const float*)d_in[9];
  const float* g2     = (const float*)d_in[10];
  const float* be2    = (const float*)d_in[11];
  const float* miss   = (const float*)d_in[12];
  float* out = (float*)d_out;
  char* ws = (char*)d_ws;

  float* rois = (float*)(ws + OFF_ROIS);
  int* det = (int*)(ws + OFF_DET);
  unsigned short* Abf = (unsigned short*)(ws + OFF_A);
  unsigned short* w1t = (unsigned short*)(ws + OFF_W1T);
  unsigned short* w2t = (unsigned short*)(ws + OFF_W2T);
  float* Gp = (float*)(ws + OFF_GP);
  unsigned short* Hbf = (unsigned short*)(ws + OFF_H);

  hipLaunchKernelGGL(select_kernel, dim3(4), dim3(256), 0, stream,
                     boxes, scores, labels, rois, det, out + (long)MROWS * FDIM);
  hipLaunchKernelGGL(roialign_kernel, dim3(BATCH, CCH / 8), dim3(256), 0, stream,
                     fm, rois, Abf);
  hipLaunchKernelGGL(wT_kernel, dim3((DDIM / 64) * (N1DIM / 64) + (N1DIM / 64) * (FDIM / 64)),
                     dim3(256), 0, stream, w1, w1t, w2, w2t);
  {
    // GEMM1: 196 k-blocks; kchunk = ceil(196/S1)*64 = 1600 (s=7 takes 1344)
    int nkb = DDIM / 64;
    int kc = ((nkb + S1 - 1) / S1) * 64;
    int gy = N1DIM / 128, nwg = 8 * gy * S1;          // 1024
    hipLaunchKernelGGL(gemm_sk_kernel, dim3(nwg), dim3(256), 0, stream,
                       Abf, w1t, Gp, MROWS, N1DIM, DDIM, kc, gy, nwg / 8);
  }
  hipLaunchKernelGGL(ln1_kernel, dim3(MROWS), dim3(256), 0, stream, Gp, b1, g1, be1, Hbf);
  // W1T dead (H aliases it); G1 partials consumed -> Gp reused for GEMM2 partials
  {
    int nkb = N1DIM / 64;
    int kc = ((nkb + S2 - 1) / S2) * 64;              // 256
    int gy = FDIM / 128, nwg = 8 * gy * S2;           // 384
    hipLaunchKernelGGL(gemm_sk_kernel, dim3(nwg), dim3(256), 0, stream,
                       Hbf, w2t, Gp, MROWS, FDIM, N1DIM, kc, gy, nwg / 8);
  }
  hipLaunchKernelGGL(ln2_kernel, dim3(MROWS), dim3(256), 0, stream,
                     Gp, b2, g2, be2, miss, det, out);
}

// Round 8
// 190.107 us; speedup vs baseline: 1.4393x; 1.4393x over previous
//
#include <hip/hip_runtime.h>

typedef __bf16 bf16x8 __attribute__((ext_vector_type(8)));
typedef float f32x4 __attribute__((ext_vector_type(4)));
typedef unsigned short ushort8v __attribute__((ext_vector_type(8)));
typedef unsigned short ushort4v __attribute__((ext_vector_type(4)));

#define BATCH 32
#define NBOX 40
#define CCH 256
#define HF 64
#define WF 64
#define RREG 29
#define OUTP 7
#define MROWS 928           // BATCH*RREG
#define DDIM 12544          // CCH*7*7
#define N1DIM 2048
#define FDIM 768
#define PDIM 4096           // HF*WF
#define S1 8                // split-K factor GEMM1
#define S2 8                // split-K factor GEMM2

// ---- workspace layout (bytes), lifetime-aliased ----
static constexpr size_t OFF_ROIS = 0;                                   // 928*4 f32
static constexpr size_t OFF_DET  = 16384;                               // 928 i32
static constexpr size_t OFF_A    = 32768;                               // bf16 [928][12544]
static constexpr size_t OFF_W1T  = OFF_A   + (size_t)MROWS * DDIM * 2;  // bf16 [2048][12544]
static constexpr size_t OFF_FMT  = OFF_W1T;                             // bf16 [32][4096][256] (dead after roi)
static constexpr size_t OFF_W2T  = OFF_W1T + (size_t)DDIM * N1DIM * 2;  // bf16 [768][2048]
static constexpr size_t OFF_GP   = OFF_W2T + (size_t)N1DIM * FDIM * 2;  // f32 [S1][928][2048]; later [S2][928][768]
static constexpr size_t OFF_H    = OFF_W1T;                             // bf16 [928][2048] (W1T dead after gemm1)

static __device__ __forceinline__ unsigned short f2bf(float f) {
  __bf16 h = (__bf16)f;
  return __builtin_bit_cast(unsigned short, h);
}
static __device__ __forceinline__ float bf2f(unsigned short u) {
  unsigned int x = ((unsigned int)u) << 16;
  return __builtin_bit_cast(float, x);
}
static __device__ __forceinline__ void gload_lds16(const void* g, void* l) {
  __builtin_amdgcn_global_load_lds((const __attribute__((address_space(1))) void*)g,
                                   (__attribute__((address_space(3))) void*)l, 16, 0, 0);
}

// ---------------- 1. select (4 blocks) + fmt NCHW f32 -> NHWC bf16 (8192 blocks) ----
__global__ __launch_bounds__(256) void selfmt_kernel(const float* __restrict__ in,
                                                     unsigned short* __restrict__ out,
                                                     const float* __restrict__ boxes,
                                                     const float* __restrict__ scores,
                                                     const int* __restrict__ labels,
                                                     float* __restrict__ rois,
                                                     int* __restrict__ det,
                                                     float* __restrict__ out_det) {
  __shared__ float tile[64][65];
  int bid = blockIdx.x;
  int t = threadIdx.x;
  if (bid >= PDIM / 64 * (CCH / 64) * BATCH) {   // ---- select part (4 trailing blocks)
    int tid = (bid - PDIM / 64 * (CCH / 64) * BATCH) * 256 + t;
    if (tid >= MROWS) return;
    int b = tid / RREG, r = tid % RREG;
    float bestS = -1.0f;
    int bestN = 0;
    int found = 0;
    for (int n = 0; n < NBOX; ++n) {
      int lab = labels[b * NBOX + n];
      int ri = min(max(lab, 1), RREG) - 1;
      if (ri == r) {
        found = 1;
        float s = scores[b * NBOX + n];
        if (s > bestS) { bestS = s; bestN = n; }
      }
    }
    const float scale = 0.0625f;
    float4 bx = *(const float4*)&boxes[(b * NBOX + bestN) * 4];
    rois[tid * 4 + 0] = bx.x * scale;
    rois[tid * 4 + 1] = bx.y * scale;
    rois[tid * 4 + 2] = bx.z * scale;
    rois[tid * 4 + 3] = bx.w * scale;
    det[tid] = found;
    out_det[tid] = found ? 1.0f : 0.0f;
    return;
  }
  // ---- fmt part
  int p0 = (bid & 63) * 64, c0 = ((bid >> 6) & 3) * 64, b = bid >> 8;
  int tx = t & 15, ty = t >> 4;
#pragma unroll
  for (int q = 0; q < 4; ++q) {
    int r = ty + q * 16;
    float4 v = *(const float4*)&in[((long)b * CCH + c0 + r) * PDIM + p0 + tx * 4];
    tile[r][tx * 4 + 0] = v.x;
    tile[r][tx * 4 + 1] = v.y;
    tile[r][tx * 4 + 2] = v.z;
    tile[r][tx * 4 + 3] = v.w;
  }
  __syncthreads();
#pragma unroll
  for (int q = 0; q < 4; ++q) {
    int r = ty + q * 16;
    ushort4v o;
    o[0] = f2bf(tile[tx * 4 + 0][r]);
    o[1] = f2bf(tile[tx * 4 + 1][r]);
    o[2] = f2bf(tile[tx * 4 + 2][r]);
    o[3] = f2bf(tile[tx * 4 + 3][r]);
    *(ushort4v*)&out[((long)b * PDIM + p0 + r) * CCH + c0 + tx * 4] = o;
  }
}

// ---------------- 2. roi align (NHWC bf16) -> bf16 [928][12544] ----------------
// thread t: channel group cg = t&63 (4 ch via ushort4 loads), bin subset sub = t>>6.
__global__ __launch_bounds__(256) void roi_kernel(const unsigned short* __restrict__ fmT,
                                                  const float* __restrict__ rois,
                                                  unsigned short* __restrict__ A) {
  __shared__ int sidx[196][4];
  __shared__ float swt[196][4];
  __shared__ unsigned short Arow[DDIM];
  int roi = blockIdx.x;
  int t = threadIdx.x;
  float rx1 = rois[roi * 4 + 0], ry1 = rois[roi * 4 + 1];
  float rx2 = rois[roi * 4 + 2], ry2 = rois[roi * 4 + 3];
  float roiw = fmaxf(rx2 - rx1, 1.f), roih = fmaxf(ry2 - ry1, 1.f);
  float bw = roiw * (1.f / OUTP), bh = roih * (1.f / OUTP);
  if (t < 196) {
    int oy = t / 28, rem = t % 28, ox = rem / 4, s = rem % 4, sy = s >> 1, sx = s & 1;
    float y = ry1 + ((float)oy + ((float)sy + 0.5f) * 0.5f) * bh;
    float x = rx1 + ((float)ox + ((float)sx + 0.5f) * 0.5f) * bw;
    bool valid = (y >= -1.f) && (y <= 64.f) && (x >= -1.f) && (x <= 64.f);
    float yc = fminf(fmaxf(y, 0.f), 63.f);
    float xc = fminf(fmaxf(x, 0.f), 63.f);
    int y0 = (int)floorf(yc), x0 = (int)floorf(xc);
    int y1i = min(y0 + 1, 63), x1i = min(x0 + 1, 63);
    float ly = yc - (float)y0, lx = xc - (float)x0;
    float hy = 1.f - ly, hx = 1.f - lx;
    float m = valid ? 1.f : 0.f;
    swt[t][0] = hy * hx * m;
    swt[t][1] = hy * lx * m;
    swt[t][2] = ly * hx * m;
    swt[t][3] = ly * lx * m;
    sidx[t][0] = (y0 * 64 + x0) * CCH;
    sidx[t][1] = (y0 * 64 + x1i) * CCH;
    sidx[t][2] = (y1i * 64 + x0) * CCH;
    sidx[t][3] = (y1i * 64 + x1i) * CCH;
  }
  __syncthreads();
  int b = roi / RREG;
  int cg = t & 63;                       // 4 channels: cg*4 .. cg*4+3
  int sub = t >> 6;                      // bin subset
  int start = sub * 12 + min(sub, 1);    // 0,13,25,37
  int cnt = sub == 0 ? 13 : 12;
  const unsigned short* base = fmT + (long)b * PDIM * CCH + cg * 4;
  for (int bi = 0; bi < cnt; ++bi) {
    int bin = start + bi;
    float a0 = 0.f, a1 = 0.f, a2 = 0.f, a3 = 0.f;
#pragma unroll
    for (int s = 0; s < 4; ++s) {
      int sid = bin * 4 + s;
#pragma unroll
      for (int tp = 0; tp < 4; ++tp) {
        float w = swt[sid][tp];
        ushort4v v = *(const ushort4v*)(base + sidx[sid][tp]);
        a0 += w * bf2f(v[0]);
        a1 += w * bf2f(v[1]);
        a2 += w * bf2f(v[2]);
        a3 += w * bf2f(v[3]);
      }
    }
    Arow[(cg * 4 + 0) * 49 + bin] = f2bf(a0 * 0.25f);
    Arow[(cg * 4 + 1) * 49 + bin] = f2bf(a1 * 0.25f);
    Arow[(cg * 4 + 2) * 49 + bin] = f2bf(a2 * 0.25f);
    Arow[(cg * 4 + 3) * 49 + bin] = f2bf(a3 * 0.25f);
  }
  __syncthreads();
  const ushort8v* src = (const ushort8v*)Arow;
  ushort8v* dst = (ushort8v*)(A + (long)roi * DDIM);
  for (int i = t; i < DDIM / 8; i += 256) dst[i] = src[i];
}

// ---------------- 3. merged transpose f32 [K][N] -> bf16 [N][K] for w1 and w2 ------
__global__ __launch_bounds__(256) void wT_kernel(const float* __restrict__ w1,
                                                 unsigned short* __restrict__ w1t,
                                                 const float* __restrict__ w2,
                                                 unsigned short* __restrict__ w2t) {
  __shared__ float tile[64][65];
  int bid = blockIdx.x;
  const float* in;
  unsigned short* out;
  int K, N, k0, n0;
  if (bid < (DDIM / 64) * (N1DIM / 64)) {
    in = w1; out = w1t; K = DDIM; N = N1DIM;
    k0 = (bid % (DDIM / 64)) * 64;
    n0 = (bid / (DDIM / 64)) * 64;
  } else {
    int r = bid - (DDIM / 64) * (N1DIM / 64);
    in = w2; out = w2t; K = N1DIM; N = FDIM;
    k0 = (r % (N1DIM / 64)) * 64;
    n0 = (r / (N1DIM / 64)) * 64;
  }
  int t = threadIdx.x, tx = t & 15, ty = t >> 4;
#pragma unroll
  for (int p = 0; p < 4; ++p) {
    int r = ty + p * 16;
    float4 v = *(const float4*)&in[(long)(k0 + r) * N + n0 + tx * 4];
    tile[r][tx * 4 + 0] = v.x;
    tile[r][tx * 4 + 1] = v.y;
    tile[r][tx * 4 + 2] = v.z;
    tile[r][tx * 4 + 3] = v.w;
  }
  __syncthreads();
#pragma unroll
  for (int p = 0; p < 4; ++p) {
    int r = ty + p * 16;
    ushort4v o;
    o[0] = f2bf(tile[tx * 4 + 0][r]);
    o[1] = f2bf(tile[tx * 4 + 1][r]);
    o[2] = f2bf(tile[tx * 4 + 2][r]);
    o[3] = f2bf(tile[tx * 4 + 3][r]);
    *(ushort4v*)&out[(long)(n0 + r) * K + k0 + tx * 4] = o;
  }
}

// ---------------- 4. split-K bf16 MFMA GEMM, counted-vmcnt pipeline ----------
__global__ __launch_bounds__(256, 2) void gemm_sk_kernel(const unsigned short* __restrict__ A,
                                                         const unsigned short* __restrict__ Bt,
                                                         float* __restrict__ Cp,
                                                         int M, int N, int K, int kchunk,
                                                         int gy, int q) {
  __shared__ unsigned short As[2 * 128 * 64];   // [buf][row][chunk^(row&7)] bf16
  __shared__ unsigned short Bs[2 * 128 * 64];
  int bid = blockIdx.x;
  int tile = (bid & 7) * q + (bid >> 3);    // bijective XCD-chunked swizzle (nwg % 8 == 0)
  int bm = tile & 7;
  int rest = tile >> 3;
  int bn = rest % gy;
  int s = rest / gy;

  int t = threadIdx.x;
  int lane = t & 63, wv = t >> 6;
  int wr = wv >> 1, wc = wv & 1;
  int fr = lane & 15, fq = lane >> 4;

  f32x4 acc[4][4];
#pragma unroll
  for (int m = 0; m < 4; ++m)
#pragma unroll
    for (int n = 0; n < 4; ++n) acc[m][n] = (f32x4){0.f, 0.f, 0.f, 0.f};

  int srow = t >> 3;
  int scol = t & 7;
  int k_begin = s * kchunk;
  int k_end = min(k_begin + kchunk, K);
  int nkt = (k_end - k_begin) >> 6;

  int garow[4], gbrow[4], schunk[4];
#pragma unroll
  for (int i = 0; i < 4; ++i) {
    int row = srow + i * 32;
    schunk[i] = (scol ^ (row & 7)) * 8;
    garow[i] = min(bm * 128 + row, M - 1);
    gbrow[i] = bn * 128 + row;
  }

#define GSTAGE(buf, kt_) do {                                                  \
    int k0_ = k_begin + (kt_) * 64;                                            \
    _Pragma("unroll")                                                          \
    for (int i = 0; i < 4; ++i)                                                \
      gload_lds16(A + (long)garow[i] * K + k0_ + schunk[i],                    \
                  (char*)As + (buf) * 16384 + t * 16 + i * 4096);              \
    _Pragma("unroll")                                                          \
    for (int i = 0; i < 4; ++i)                                                \
      gload_lds16(Bt + (long)gbrow[i] * K + k0_ + schunk[i],                   \
                  (char*)Bs + (buf) * 16384 + t * 16 + i * 4096);              \
  } while (0)

  GSTAGE(0, 0);
  GSTAGE(1, min(1, nkt - 1));

  for (int kt = 0; kt < nkt; ++kt) {
    int cur = kt & 1;
    asm volatile("s_waitcnt vmcnt(8)" ::: "memory");
    __builtin_amdgcn_sched_barrier(0);
    __builtin_amdgcn_s_barrier();
    __builtin_amdgcn_sched_barrier(0);

    const char* Ab = (const char*)As + cur * 16384;
    const char* Bb = (const char*)Bs + cur * 16384;
#pragma unroll
    for (int ks = 0; ks < 2; ++ks) {
      bf16x8 af[4], bfv[4];
#pragma unroll
      for (int m = 0; m < 4; ++m) {
        int row = wr * 64 + m * 16 + fr;
        int bc = (ks * 64 + fq * 16) ^ ((row & 7) << 4);
        af[m] = *(const bf16x8*)(Ab + row * 128 + bc);
      }
#pragma unroll
      for (int n = 0; n < 4; ++n) {
        int row = wc * 64 + n * 16 + fr;
        int bc = (ks * 64 + fq * 16) ^ ((row & 7) << 4);
        bfv[n] = *(const bf16x8*)(Bb + row * 128 + bc);
      }
#pragma unroll
      for (int m = 0; m < 4; ++m)
#pragma unroll
        for (int n = 0; n < 4; ++n)
          acc[m][n] = __builtin_amdgcn_mfma_f32_16x16x32_bf16(af[m], bfv[n], acc[m][n], 0, 0, 0);
    }

    __builtin_amdgcn_sched_barrier(0);
    __builtin_amdgcn_s_barrier();
    __builtin_amdgcn_sched_barrier(0);
    GSTAGE(cur, min(kt + 2, nkt - 1));
  }
#undef GSTAGE

  float* Cb = Cp + (long)s * M * N;
#pragma unroll
  for (int m = 0; m < 4; ++m)
#pragma unroll
    for (int n = 0; n < 4; ++n) {
      int col = bn * 128 + wc * 64 + n * 16 + fr;
#pragma unroll
      for (int j = 0; j < 4; ++j) {
        int row = bm * 128 + wr * 64 + m * 16 + fq * 4 + j;
        if (row < M) Cb[(long)row * N + col] = acc[m][n][j];
      }
    }
}

// ---------------- block reduce helper ----------------
static __device__ __forceinline__ void block_reduce2(float& a, float& b, float* sm) {
#pragma unroll
  for (int off = 32; off > 0; off >>= 1) {
    a += __shfl_down(a, off);
    b += __shfl_down(b, off);
  }
  int lane = threadIdx.x & 63, wv = threadIdx.x >> 6;
  if (lane == 0) { sm[wv] = a; sm[wv + 4] = b; }
  __syncthreads();
  a = sm[0] + sm[1] + sm[2] + sm[3];
  b = sm[4] + sm[5] + sm[6] + sm[7];
}

// ---------------- 5. partial-sum + bias + LN + ReLU -> bf16 h ----------------
__global__ __launch_bounds__(256) void ln1_kernel(const float* __restrict__ X,
                                                  const float* __restrict__ b1,
                                                  const float* __restrict__ g1,
                                                  const float* __restrict__ be1,
                                                  unsigned short* __restrict__ H) {
  __shared__ float sm[8];
  int row = blockIdx.x, t = threadIdx.x;
  float x[8];
  float sum = 0.f, sq = 0.f;
#pragma unroll
  for (int i = 0; i < 8; ++i) {
    int j = t + i * 256;
    float v = b1[j];
#pragma unroll
    for (int s = 0; s < S1; ++s) v += X[((long)s * MROWS + row) * N1DIM + j];
    x[i] = v;
    sum += v;
    sq += v * v;
  }
  block_reduce2(sum, sq, sm);
  float mu = sum * (1.f / N1DIM);
  float inv = rsqrtf(sq * (1.f / N1DIM) - mu * mu + 1e-5f);
#pragma unroll
  for (int i = 0; i < 8; ++i) {
    int j = t + i * 256;
    float y = fmaxf((x[i] - mu) * inv * g1[j] + be1[j], 0.f);
    H[(long)row * N1DIM + j] = f2bf(y);
  }
}

// ---------------- 6. partial-sum + bias + LN + missing-token -> out ----------------
__global__ __launch_bounds__(256) void ln2_kernel(const float* __restrict__ X,
                                                  const float* __restrict__ b2,
                                                  const float* __restrict__ g2,
                                                  const float* __restrict__ be2,
                                                  const float* __restrict__ miss,
                                                  const int* __restrict__ det,
                                                  float* __restrict__ out) {
  __shared__ float sm[8];
  int row = blockIdx.x, t = threadIdx.x;
  float x[3];
  float sum = 0.f, sq = 0.f;
#pragma unroll
  for (int i = 0; i < 3; ++i) {
    int j = t + i * 256;
    float v = b2[j];
#pragma unroll
    for (int s = 0; s < S2; ++s) v += X[((long)s * MROWS + row) * FDIM + j];
    x[i] = v;
    sum += v;
    sq += v * v;
  }
  block_reduce2(sum, sq, sm);
  float mu = sum * (1.f / FDIM);
  float inv = rsqrtf(sq * (1.f / FDIM) - mu * mu + 1e-5f);
  int dv = det[row];
#pragma unroll
  for (int i = 0; i < 3; ++i) {
    int j = t + i * 256;
    float y = (x[i] - mu) * inv * g2[j] + be2[j];
    out[(long)row * FDIM + j] = dv ? y : miss[j];
  }
}

extern "C" void kernel_launch(void* const* d_in, const int* in_sizes, int n_in,
                              void* d_out, int out_size, void* d_ws, size_t ws_size,
                              hipStream_t stream) {
  const float* fm     = (const float*)d_in[0];
  const float* boxes  = (const float*)d_in[1];
  const float* scores = (const float*)d_in[2];
  const int*   labels = (const int*)d_in[3];
  const float* w1     = (const float*)d_in[4];
  const float* b1     = (const float*)d_in[5];
  const float* g1     = (const float*)d_in[6];
  const float* be1    = (const float*)d_in[7];
  const float* w2     = (const float*)d_in[8];
  const float* b2     = (const float*)d_in[9];
  const float* g2     = (const float*)d_in[10];
  const float* be2    = (const float*)d_in[11];
  const float* miss   = (const float*)d_in[12];
  float* out = (float*)d_out;
  char* ws = (char*)d_ws;

  float* rois = (float*)(ws + OFF_ROIS);
  int* det = (int*)(ws + OFF_DET);
  unsigned short* Abf = (unsigned short*)(ws + OFF_A);
  unsigned short* fmT = (unsigned short*)(ws + OFF_FMT);
  unsigned short* w1t = (unsigned short*)(ws + OFF_W1T);
  unsigned short* w2t = (unsigned short*)(ws + OFF_W2T);
  float* Gp = (float*)(ws + OFF_GP);
  unsigned short* Hbf = (unsigned short*)(ws + OFF_H);

  // select (4 blocks) + fmt (8192 blocks)
  hipLaunchKernelGGL(selfmt_kernel, dim3(8192 + 4), dim3(256), 0, stream,
                     fm, fmT, boxes, scores, labels, rois, det, out + (long)MROWS * FDIM);
  hipLaunchKernelGGL(roi_kernel, dim3(MROWS), dim3(256), 0, stream, fmT, rois, Abf);
  // fmT dead; w1t/w2t overwrite its region (stream-ordered)
  hipLaunchKernelGGL(wT_kernel, dim3((DDIM / 64) * (N1DIM / 64) + (N1DIM / 64) * (FDIM / 64)),
                     dim3(256), 0, stream, w1, w1t, w2, w2t);
  {
    // GEMM1: 196 k-blocks; kchunk = ceil(196/S1)*64 = 1600 (s=7 takes 1344)
    int nkb = DDIM / 64;
    int kc = ((nkb + S1 - 1) / S1) * 64;
    int gy = N1DIM / 128, nwg = 8 * gy * S1;          // 1024
    hipLaunchKernelGGL(gemm_sk_kernel, dim3(nwg), dim3(256), 0, stream,
                       Abf, w1t, Gp, MROWS, N1DIM, DDIM, kc, gy, nwg / 8);
  }
  hipLaunchKernelGGL(ln1_kernel, dim3(MROWS), dim3(256), 0, stream, Gp, b1, g1, be1, Hbf);
  // W1T dead (H aliases it); G1 partials consumed -> Gp reused for GEMM2 partials
  {
    int nkb = N1DIM / 64;
    int kc = ((nkb + S2 - 1) / S2) * 64;              // 256
    int gy = FDIM / 128, nwg = 8 * gy * S2;           // 384
    hipLaunchKernelGGL(gemm_sk_kernel, dim3(nwg), dim3(256), 0, stream,
                       Hbf, w2t, Gp, MROWS, FDIM, N1DIM, kc, gy, nwg / 8);
  }
  hipLaunchKernelGGL(ln2_kernel, dim3(MROWS), dim3(256), 0, stream,
                     Gp, b2, g2, be2, miss, det, out);
}

// Round 9
// 183.284 us; speedup vs baseline: 1.4929x; 1.0372x over previous
//
#include <hip/hip_runtime.h>

typedef __bf16 bf16x8 __attribute__((ext_vector_type(8)));
typedef float f32x4 __attribute__((ext_vector_type(4)));
typedef unsigned short ushort8v __attribute__((ext_vector_type(8)));
typedef unsigned short ushort4v __attribute__((ext_vector_type(4)));

#define BATCH 32
#define NBOX 40
#define CCH 256
#define HF 64
#define WF 64
#define RREG 29
#define OUTP 7
#define MROWS 928           // BATCH*RREG
#define DDIM 12544          // CCH*7*7
#define N1DIM 2048
#define FDIM 768
#define PDIM 4096           // HF*WF
#define S1 4                // split-K factor GEMM1 (196/4 = 49 K-tiles exact; grid 512 = 2/CU)
#define S2 8                // split-K factor GEMM2

// ---- workspace layout (bytes), lifetime-aliased ----
static constexpr size_t OFF_ROIS = 0;                                   // 928*4 f32
static constexpr size_t OFF_DET  = 16384;                               // 928 i32
static constexpr size_t OFF_A    = 32768;                               // bf16 [928][12544]
static constexpr size_t OFF_W1T  = OFF_A   + (size_t)MROWS * DDIM * 2;  // bf16 [2048][12544]
static constexpr size_t OFF_FMT  = OFF_W1T;                             // bf16 [32][4096][256] (dead after roi)
static constexpr size_t OFF_W2T  = OFF_W1T + (size_t)DDIM * N1DIM * 2;  // bf16 [768][2048]
static constexpr size_t OFF_GP   = OFF_W2T + (size_t)N1DIM * FDIM * 2;  // f32 [S1][928][2048]; later [S2][928][768]
static constexpr size_t OFF_H    = OFF_W1T;                             // bf16 [928][2048] (W1T dead after gemm1)

static __device__ __forceinline__ unsigned short f2bf(float f) {
  __bf16 h = (__bf16)f;
  return __builtin_bit_cast(unsigned short, h);
}
static __device__ __forceinline__ float bf2f(unsigned short u) {
  unsigned int x = ((unsigned int)u) << 16;
  return __builtin_bit_cast(float, x);
}
static __device__ __forceinline__ void gload_lds16(const void* g, void* l) {
  __builtin_amdgcn_global_load_lds((const __attribute__((address_space(1))) void*)g,
                                   (__attribute__((address_space(3))) void*)l, 16, 0, 0);
}

// ---------------- 1. select (4 blocks) + fmt NCHW f32 -> NHWC bf16 (8192 blocks) ----
__global__ __launch_bounds__(256) void selfmt_kernel(const float* __restrict__ in,
                                                     unsigned short* __restrict__ out,
                                                     const float* __restrict__ boxes,
                                                     const float* __restrict__ scores,
                                                     const int* __restrict__ labels,
                                                     float* __restrict__ rois,
                                                     int* __restrict__ det,
                                                     float* __restrict__ out_det) {
  __shared__ float tile[64][65];
  int bid = blockIdx.x;
  int t = threadIdx.x;
  if (bid >= PDIM / 64 * (CCH / 64) * BATCH) {   // ---- select part (4 trailing blocks)
    int tid = (bid - PDIM / 64 * (CCH / 64) * BATCH) * 256 + t;
    if (tid >= MROWS) return;
    int b = tid / RREG, r = tid % RREG;
    float bestS = -1.0f;
    int bestN = 0;
    int found = 0;
    for (int n = 0; n < NBOX; ++n) {
      int lab = labels[b * NBOX + n];
      int ri = min(max(lab, 1), RREG) - 1;
      if (ri == r) {
        found = 1;
        float s = scores[b * NBOX + n];
        if (s > bestS) { bestS = s; bestN = n; }
      }
    }
    const float scale = 0.0625f;
    float4 bx = *(const float4*)&boxes[(b * NBOX + bestN) * 4];
    rois[tid * 4 + 0] = bx.x * scale;
    rois[tid * 4 + 1] = bx.y * scale;
    rois[tid * 4 + 2] = bx.z * scale;
    rois[tid * 4 + 3] = bx.w * scale;
    det[tid] = found;
    out_det[tid] = found ? 1.0f : 0.0f;
    return;
  }
  // ---- fmt part
  int p0 = (bid & 63) * 64, c0 = ((bid >> 6) & 3) * 64, b = bid >> 8;
  int tx = t & 15, ty = t >> 4;
#pragma unroll
  for (int q = 0; q < 4; ++q) {
    int r = ty + q * 16;
    float4 v = *(const float4*)&in[((long)b * CCH + c0 + r) * PDIM + p0 + tx * 4];
    tile[r][tx * 4 + 0] = v.x;
    tile[r][tx * 4 + 1] = v.y;
    tile[r][tx * 4 + 2] = v.z;
    tile[r][tx * 4 + 3] = v.w;
  }
  __syncthreads();
#pragma unroll
  for (int q = 0; q < 4; ++q) {
    int r = ty + q * 16;
    ushort4v o;
    o[0] = f2bf(tile[tx * 4 + 0][r]);
    o[1] = f2bf(tile[tx * 4 + 1][r]);
    o[2] = f2bf(tile[tx * 4 + 2][r]);
    o[3] = f2bf(tile[tx * 4 + 3][r]);
    *(ushort4v*)&out[((long)b * PDIM + p0 + r) * CCH + c0 + tx * 4] = o;
  }
}

// ---------------- 2. roi align (NHWC bf16) -> bf16 [928][12544] ----------------
// thread t: channel group cg = t&63 (4 ch via ushort4 loads), bin subset sub = t>>6.
__global__ __launch_bounds__(256) void roi_kernel(const unsigned short* __restrict__ fmT,
                                                  const float* __restrict__ rois,
                                                  unsigned short* __restrict__ A) {
  __shared__ int sidx[196][4];
  __shared__ float swt[196][4];
  __shared__ unsigned short Arow[DDIM];
  int roi = blockIdx.x;
  int t = threadIdx.x;
  float rx1 = rois[roi * 4 + 0], ry1 = rois[roi * 4 + 1];
  float rx2 = rois[roi * 4 + 2], ry2 = rois[roi * 4 + 3];
  float roiw = fmaxf(rx2 - rx1, 1.f), roih = fmaxf(ry2 - ry1, 1.f);
  float bw = roiw * (1.f / OUTP), bh = roih * (1.f / OUTP);
  if (t < 196) {
    int oy = t / 28, rem = t % 28, ox = rem / 4, s = rem % 4, sy = s >> 1, sx = s & 1;
    float y = ry1 + ((float)oy + ((float)sy + 0.5f) * 0.5f) * bh;
    float x = rx1 + ((float)ox + ((float)sx + 0.5f) * 0.5f) * bw;
    bool valid = (y >= -1.f) && (y <= 64.f) && (x >= -1.f) && (x <= 64.f);
    float yc = fminf(fmaxf(y, 0.f), 63.f);
    float xc = fminf(fmaxf(x, 0.f), 63.f);
    int y0 = (int)floorf(yc), x0 = (int)floorf(xc);
    int y1i = min(y0 + 1, 63), x1i = min(x0 + 1, 63);
    float ly = yc - (float)y0, lx = xc - (float)x0;
    float hy = 1.f - ly, hx = 1.f - lx;
    float m = valid ? 1.f : 0.f;
    swt[t][0] = hy * hx * m;
    swt[t][1] = hy * lx * m;
    swt[t][2] = ly * hx * m;
    swt[t][3] = ly * lx * m;
    sidx[t][0] = (y0 * 64 + x0) * CCH;
    sidx[t][1] = (y0 * 64 + x1i) * CCH;
    sidx[t][2] = (y1i * 64 + x0) * CCH;
    sidx[t][3] = (y1i * 64 + x1i) * CCH;
  }
  __syncthreads();
  int b = roi / RREG;
  int cg = t & 63;                       // 4 channels: cg*4 .. cg*4+3
  int sub = t >> 6;                      // bin subset
  int start = sub * 12 + min(sub, 1);    // 0,13,25,37
  int cnt = sub == 0 ? 13 : 12;
  const unsigned short* base = fmT + (long)b * PDIM * CCH + cg * 4;
  for (int bi = 0; bi < cnt; ++bi) {
    int bin = start + bi;
    float a0 = 0.f, a1 = 0.f, a2 = 0.f, a3 = 0.f;
#pragma unroll
    for (int s = 0; s < 4; ++s) {
      int sid = bin * 4 + s;
#pragma unroll
      for (int tp = 0; tp < 4; ++tp) {
        float w = swt[sid][tp];
        ushort4v v = *(const ushort4v*)(base + sidx[sid][tp]);
        a0 += w * bf2f(v[0]);
        a1 += w * bf2f(v[1]);
        a2 += w * bf2f(v[2]);
        a3 += w * bf2f(v[3]);
      }
    }
    Arow[(cg * 4 + 0) * 49 + bin] = f2bf(a0 * 0.25f);
    Arow[(cg * 4 + 1) * 49 + bin] = f2bf(a1 * 0.25f);
    Arow[(cg * 4 + 2) * 49 + bin] = f2bf(a2 * 0.25f);
    Arow[(cg * 4 + 3) * 49 + bin] = f2bf(a3 * 0.25f);
  }
  __syncthreads();
  const ushort8v* src = (const ushort8v*)Arow;
  ushort8v* dst = (ushort8v*)(A + (long)roi * DDIM);
  for (int i = t; i < DDIM / 8; i += 256) dst[i] = src[i];
}

// ---------------- 3. merged transpose f32 [K][N] -> bf16 [N][K] for w1 and w2 ------
__global__ __launch_bounds__(256) void wT_kernel(const float* __restrict__ w1,
                                                 unsigned short* __restrict__ w1t,
                                                 const float* __restrict__ w2,
                                                 unsigned short* __restrict__ w2t) {
  __shared__ float tile[64][65];
  int bid = blockIdx.x;
  const float* in;
  unsigned short* out;
  int K, N, k0, n0;
  if (bid < (DDIM / 64) * (N1DIM / 64)) {
    in = w1; out = w1t; K = DDIM; N = N1DIM;
    k0 = (bid % (DDIM / 64)) * 64;
    n0 = (bid / (DDIM / 64)) * 64;
  } else {
    int r = bid - (DDIM / 64) * (N1DIM / 64);
    in = w2; out = w2t; K = N1DIM; N = FDIM;
    k0 = (r % (N1DIM / 64)) * 64;
    n0 = (r / (N1DIM / 64)) * 64;
  }
  int t = threadIdx.x, tx = t & 15, ty = t >> 4;
#pragma unroll
  for (int p = 0; p < 4; ++p) {
    int r = ty + p * 16;
    float4 v = *(const float4*)&in[(long)(k0 + r) * N + n0 + tx * 4];
    tile[r][tx * 4 + 0] = v.x;
    tile[r][tx * 4 + 1] = v.y;
    tile[r][tx * 4 + 2] = v.z;
    tile[r][tx * 4 + 3] = v.w;
  }
  __syncthreads();
#pragma unroll
  for (int p = 0; p < 4; ++p) {
    int r = ty + p * 16;
    ushort4v o;
    o[0] = f2bf(tile[tx * 4 + 0][r]);
    o[1] = f2bf(tile[tx * 4 + 1][r]);
    o[2] = f2bf(tile[tx * 4 + 2][r]);
    o[3] = f2bf(tile[tx * 4 + 3][r]);
    *(ushort4v*)&out[(long)(n0 + r) * K + k0 + tx * 4] = o;
  }
}

// ---------------- 4. split-K bf16 MFMA GEMM, counted-vmcnt pipeline ----------
__global__ __launch_bounds__(256, 2) void gemm_sk_kernel(const unsigned short* __restrict__ A,
                                                         const unsigned short* __restrict__ Bt,
                                                         float* __restrict__ Cp,
                                                         int M, int N, int K, int kchunk,
                                                         int gy, int q) {
  __shared__ unsigned short As[2 * 128 * 64];   // [buf][row][chunk^(row&7)] bf16
  __shared__ unsigned short Bs[2 * 128 * 64];
  int bid = blockIdx.x;
  int tile = (bid & 7) * q + (bid >> 3);    // bijective XCD-chunked swizzle (nwg % 8 == 0)
  int bm = tile & 7;
  int rest = tile >> 3;
  int bn = rest % gy;
  int s = rest / gy;

  int t = threadIdx.x;
  int lane = t & 63, wv = t >> 6;
  int wr = wv >> 1, wc = wv & 1;
  int fr = lane & 15, fq = lane >> 4;

  f32x4 acc[4][4];
#pragma unroll
  for (int m = 0; m < 4; ++m)
#pragma unroll
    for (int n = 0; n < 4; ++n) acc[m][n] = (f32x4){0.f, 0.f, 0.f, 0.f};

  int srow = t >> 3;
  int scol = t & 7;
  int k_begin = s * kchunk;
  int k_end = min(k_begin + kchunk, K);
  int nkt = (k_end - k_begin) >> 6;

  int garow[4], gbrow[4], schunk[4];
#pragma unroll
  for (int i = 0; i < 4; ++i) {
    int row = srow + i * 32;
    schunk[i] = (scol ^ (row & 7)) * 8;
    garow[i] = min(bm * 128 + row, M - 1);
    gbrow[i] = bn * 128 + row;
  }

#define GSTAGE(buf, kt_) do {                                                  \
    int k0_ = k_begin + (kt_) * 64;                                            \
    _Pragma("unroll")                                                          \
    for (int i = 0; i < 4; ++i)                                                \
      gload_lds16(A + (long)garow[i] * K + k0_ + schunk[i],                    \
                  (char*)As + (buf) * 16384 + t * 16 + i * 4096);              \
    _Pragma("unroll")                                                          \
    for (int i = 0; i < 4; ++i)                                                \
      gload_lds16(Bt + (long)gbrow[i] * K + k0_ + schunk[i],                   \
                  (char*)Bs + (buf) * 16384 + t * 16 + i * 4096);              \
  } while (0)

  GSTAGE(0, 0);
  GSTAGE(1, min(1, nkt - 1));

  for (int kt = 0; kt < nkt; ++kt) {
    int cur = kt & 1;
    asm volatile("s_waitcnt vmcnt(8)" ::: "memory");
    __builtin_amdgcn_sched_barrier(0);
    __builtin_amdgcn_s_barrier();
    __builtin_amdgcn_sched_barrier(0);

    const char* Ab = (const char*)As + cur * 16384;
    const char* Bb = (const char*)Bs + cur * 16384;
#pragma unroll
    for (int ks = 0; ks < 2; ++ks) {
      bf16x8 af[4], bfv[4];
#pragma unroll
      for (int m = 0; m < 4; ++m) {
        int row = wr * 64 + m * 16 + fr;
        int bc = (ks * 64 + fq * 16) ^ ((row & 7) << 4);
        af[m] = *(const bf16x8*)(Ab + row * 128 + bc);
      }
#pragma unroll
      for (int n = 0; n < 4; ++n) {
        int row = wc * 64 + n * 16 + fr;
        int bc = (ks * 64 + fq * 16) ^ ((row & 7) << 4);
        bfv[n] = *(const bf16x8*)(Bb + row * 128 + bc);
      }
#pragma unroll
      for (int m = 0; m < 4; ++m)
#pragma unroll
        for (int n = 0; n < 4; ++n)
          acc[m][n] = __builtin_amdgcn_mfma_f32_16x16x32_bf16(af[m], bfv[n], acc[m][n], 0, 0, 0);
    }

    __builtin_amdgcn_sched_barrier(0);
    __builtin_amdgcn_s_barrier();
    __builtin_amdgcn_sched_barrier(0);
    GSTAGE(cur, min(kt + 2, nkt - 1));
  }
#undef GSTAGE

  float* Cb = Cp + (long)s * M * N;
#pragma unroll
  for (int m = 0; m < 4; ++m)
#pragma unroll
    for (int n = 0; n < 4; ++n) {
      int col = bn * 128 + wc * 64 + n * 16 + fr;
#pragma unroll
      for (int j = 0; j < 4; ++j) {
        int row = bm * 128 + wr * 64 + m * 16 + fq * 4 + j;
        if (row < M) Cb[(long)row * N + col] = acc[m][n][j];
      }
    }
}

// ---------------- block reduce helper ----------------
static __device__ __forceinline__ void block_reduce2(float& a, float& b, float* sm) {
#pragma unroll
  for (int off = 32; off > 0; off >>= 1) {
    a += __shfl_down(a, off);
    b += __shfl_down(b, off);
  }
  int lane = threadIdx.x & 63, wv = threadIdx.x >> 6;
  if (lane == 0) { sm[wv] = a; sm[wv + 4] = b; }
  __syncthreads();
  a = sm[0] + sm[1] + sm[2] + sm[3];
  b = sm[4] + sm[5] + sm[6] + sm[7];
}

// ---------------- 5. partial-sum + bias + LN + ReLU -> bf16 h ----------------
__global__ __launch_bounds__(256) void ln1_kernel(const float* __restrict__ X,
                                                  const float* __restrict__ b1,
                                                  const float* __restrict__ g1,
                                                  const float* __restrict__ be1,
                                                  unsigned short* __restrict__ H) {
  __shared__ float sm[8];
  int row = blockIdx.x, t = threadIdx.x;
  float x[8];
  float sum = 0.f, sq = 0.f;
#pragma unroll
  for (int i = 0; i < 8; ++i) {
    int j = t + i * 256;
    float v = b1[j];
#pragma unroll
    for (int s = 0; s < S1; ++s) v += X[((long)s * MROWS + row) * N1DIM + j];
    x[i] = v;
    sum += v;
    sq += v * v;
  }
  block_reduce2(sum, sq, sm);
  float mu = sum * (1.f / N1DIM);
  float inv = rsqrtf(sq * (1.f / N1DIM) - mu * mu + 1e-5f);
#pragma unroll
  for (int i = 0; i < 8; ++i) {
    int j = t + i * 256;
    float y = fmaxf((x[i] - mu) * inv * g1[j] + be1[j], 0.f);
    H[(long)row * N1DIM + j] = f2bf(y);
  }
}

// ---------------- 6. partial-sum + bias + LN + missing-token -> out ----------------
__global__ __launch_bounds__(256) void ln2_kernel(const float* __restrict__ X,
                                                  const float* __restrict__ b2,
                                                  const float* __restrict__ g2,
                                                  const float* __restrict__ be2,
                                                  const float* __restrict__ miss,
                                                  const int* __restrict__ det,
                                                  float* __restrict__ out) {
  __shared__ float sm[8];
  int row = blockIdx.x, t = threadIdx.x;
  float x[3];
  float sum = 0.f, sq = 0.f;
#pragma unroll
  for (int i = 0; i < 3; ++i) {
    int j = t + i * 256;
    float v = b2[j];
#pragma unroll
    for (int s = 0; s < S2; ++s) v += X[((long)s * MROWS + row) * FDIM + j];
    x[i] = v;
    sum += v;
    sq += v * v;
  }
  block_reduce2(sum, sq, sm);
  float mu = sum * (1.f / FDIM);
  float inv = rsqrtf(sq * (1.f / FDIM) - mu * mu + 1e-5f);
  int dv = det[row];
#pragma unroll
  for (int i = 0; i < 3; ++i) {
    int j = t + i * 256;
    float y = (x[i] - mu) * inv * g2[j] + be2[j];
    out[(long)row * FDIM + j] = dv ? y : miss[j];
  }
}

extern "C" void kernel_launch(void* const* d_in, const int* in_sizes, int n_in,
                              void* d_out, int out_size, void* d_ws, size_t ws_size,
                              hipStream_t stream) {
  const float* fm     = (const float*)d_in[0];
  const float* boxes  = (const float*)d_in[1];
  const float* scores = (const float*)d_in[2];
  const int*   labels = (const int*)d_in[3];
  const float* w1     = (const float*)d_in[4];
  const float* b1     = (const float*)d_in[5];
  const float* g1     = (const float*)d_in[6];
  const float* be1    = (const float*)d_in[7];
  const float* w2     = (const float*)d_in[8];
  const float* b2     = (const float*)d_in[9];
  const float* g2     = (const float*)d_in[10];
  const float* be2    = (const float*)d_in[11];
  const float* miss   = (const float*)d_in[12];
  float* out = (float*)d_out;
  char* ws = (char*)d_ws;

  float* rois = (float*)(ws + OFF_ROIS);
  int* det = (int*)(ws + OFF_DET);
  unsigned short* Abf = (unsigned short*)(ws + OFF_A);
  unsigned short* fmT = (unsigned short*)(ws + OFF_FMT);
  unsigned short* w1t = (unsigned short*)(ws + OFF_W1T);
  unsigned short* w2t = (unsigned short*)(ws + OFF_W2T);
  float* Gp = (float*)(ws + OFF_GP);
  unsigned short* Hbf = (unsigned short*)(ws + OFF_H);

  // select (4 blocks) + fmt (8192 blocks)
  hipLaunchKernelGGL(selfmt_kernel, dim3(8192 + 4), dim3(256), 0, stream,
                     fm, fmT, boxes, scores, labels, rois, det, out + (long)MROWS * FDIM);
  hipLaunchKernelGGL(roi_kernel, dim3(MROWS), dim3(256), 0, stream, fmT, rois, Abf);
  // fmT dead; w1t/w2t overwrite its region (stream-ordered)
  hipLaunchKernelGGL(wT_kernel, dim3((DDIM / 64) * (N1DIM / 64) + (N1DIM / 64) * (FDIM / 64)),
                     dim3(256), 0, stream, w1, w1t, w2, w2t);
  {
    // GEMM1: 196 k-blocks; kchunk = 49*64 = 3136, exact for all 4 splits
    int nkb = DDIM / 64;
    int kc = ((nkb + S1 - 1) / S1) * 64;
    int gy = N1DIM / 128, nwg = 8 * gy * S1;          // 512 = 2 blocks/CU exactly
    hipLaunchKernelGGL(gemm_sk_kernel, dim3(nwg), dim3(256), 0, stream,
                       Abf, w1t, Gp, MROWS, N1DIM, DDIM, kc, gy, nwg / 8);
  }
  hipLaunchKernelGGL(ln1_kernel, dim3(MROWS), dim3(256), 0, stream, Gp, b1, g1, be1, Hbf);
  // W1T dead (H aliases it); G1 partials consumed -> Gp reused for GEMM2 partials
  {
    int nkb = N1DIM / 64;
    int kc = ((nkb + S2 - 1) / S2) * 64;              // 256
    int gy = FDIM / 128, nwg = 8 * gy * S2;           // 384
    hipLaunchKernelGGL(gemm_sk_kernel, dim3(nwg), dim3(256), 0, stream,
                       Hbf, w2t, Gp, MROWS, FDIM, N1DIM, kc, gy, nwg / 8);
  }
  hipLaunchKernelGGL(ln2_kernel, dim3(MROWS), dim3(256), 0, stream,
                     Gp, b2, g2, be2, miss, det, out);
}

// Round 10
// 178.049 us; speedup vs baseline: 1.5367x; 1.0294x over previous
//
#include <hip/hip_runtime.h>

typedef __bf16 bf16x8 __attribute__((ext_vector_type(8)));
typedef float f32x4 __attribute__((ext_vector_type(4)));
typedef unsigned short ushort8v __attribute__((ext_vector_type(8)));
typedef unsigned short ushort4v __attribute__((ext_vector_type(4)));

#define BATCH 32
#define NBOX 40
#define CCH 256
#define HF 64
#define WF 64
#define RREG 29
#define OUTP 7
#define MROWS 928           // BATCH*RREG
#define DDIM 12544          // CCH*7*7
#define N1DIM 2048
#define FDIM 768
#define PDIM 4096           // HF*WF
#define S1 4                // split-K factor GEMM1 (196/4 = 49 K-tiles exact)
#define S2 8                // split-K factor GEMM2

// ---- workspace layout (bytes). fmT now has its own region (roi runs
// concurrently with wT, so fmT must NOT alias w1t). Peak ~172 MB < 512 MiB ws.
static constexpr size_t OFF_ROIS = 0;                                   // 928*4 f32
static constexpr size_t OFF_DET  = 16384;                               // 928 i32
static constexpr size_t OFF_A    = 32768;                               // bf16 [928][12544]
static constexpr size_t OFF_W1T  = OFF_A   + (size_t)MROWS * DDIM * 2;  // bf16 [2048][12544]
static constexpr size_t OFF_W2T  = OFF_W1T + (size_t)DDIM * N1DIM * 2;  // bf16 [768][2048]
static constexpr size_t OFF_GP   = OFF_W2T + (size_t)N1DIM * FDIM * 2;  // f32 [S1][928][2048] / [S2][928][768]
static constexpr size_t OFF_FMT  = OFF_GP  + (size_t)S1 * MROWS * N1DIM * 4; // bf16 [32][4096][256]
static constexpr size_t OFF_H    = OFF_W1T;                             // bf16 [928][2048] (W1T dead after gemm1)

static __device__ __forceinline__ unsigned short f2bf(float f) {
  __bf16 h = (__bf16)f;
  return __builtin_bit_cast(unsigned short, h);
}
static __device__ __forceinline__ float bf2f(unsigned short u) {
  unsigned int x = ((unsigned int)u) << 16;
  return __builtin_bit_cast(float, x);
}
static __device__ __forceinline__ void gload_lds16(const void* g, void* l) {
  __builtin_amdgcn_global_load_lds((const __attribute__((address_space(1))) void*)g,
                                   (__attribute__((address_space(3))) void*)l, 16, 0, 0);
}

// ---------------- 1. select (4 blocks) + fmt NCHW f32 -> NHWC bf16 (8192 blocks) ----
__global__ __launch_bounds__(256) void selfmt_kernel(const float* __restrict__ in,
                                                     unsigned short* __restrict__ out,
                                                     const float* __restrict__ boxes,
                                                     const float* __restrict__ scores,
                                                     const int* __restrict__ labels,
                                                     float* __restrict__ rois,
                                                     int* __restrict__ det,
                                                     float* __restrict__ out_det) {
  __shared__ float tile[64][65];
  int bid = blockIdx.x;
  int t = threadIdx.x;
  if (bid >= PDIM / 64 * (CCH / 64) * BATCH) {   // ---- select part (4 trailing blocks)
    int tid = (bid - PDIM / 64 * (CCH / 64) * BATCH) * 256 + t;
    if (tid >= MROWS) return;
    int b = tid / RREG, r = tid % RREG;
    float bestS = -1.0f;
    int bestN = 0;
    int found = 0;
    for (int n = 0; n < NBOX; ++n) {
      int lab = labels[b * NBOX + n];
      int ri = min(max(lab, 1), RREG) - 1;
      if (ri == r) {
        found = 1;
        float s = scores[b * NBOX + n];
        if (s > bestS) { bestS = s; bestN = n; }
      }
    }
    const float scale = 0.0625f;
    float4 bx = *(const float4*)&boxes[(b * NBOX + bestN) * 4];
    rois[tid * 4 + 0] = bx.x * scale;
    rois[tid * 4 + 1] = bx.y * scale;
    rois[tid * 4 + 2] = bx.z * scale;
    rois[tid * 4 + 3] = bx.w * scale;
    det[tid] = found;
    out_det[tid] = found ? 1.0f : 0.0f;
    return;
  }
  // ---- fmt part
  int p0 = (bid & 63) * 64, c0 = ((bid >> 6) & 3) * 64, b = bid >> 8;
  int tx = t & 15, ty = t >> 4;
#pragma unroll
  for (int q = 0; q < 4; ++q) {
    int r = ty + q * 16;
    float4 v = *(const float4*)&in[((long)b * CCH + c0 + r) * PDIM + p0 + tx * 4];
    tile[r][tx * 4 + 0] = v.x;
    tile[r][tx * 4 + 1] = v.y;
    tile[r][tx * 4 + 2] = v.z;
    tile[r][tx * 4 + 3] = v.w;
  }
  __syncthreads();
#pragma unroll
  for (int q = 0; q < 4; ++q) {
    int r = ty + q * 16;
    ushort4v o;
    o[0] = f2bf(tile[tx * 4 + 0][r]);
    o[1] = f2bf(tile[tx * 4 + 1][r]);
    o[2] = f2bf(tile[tx * 4 + 2][r]);
    o[3] = f2bf(tile[tx * 4 + 3][r]);
    *(ushort4v*)&out[((long)b * PDIM + p0 + r) * CCH + c0 + tx * 4] = o;
  }
}

// ---------------- 2. merged roi-align (latency-bound) + weight transpose (BW-bound) ----
// blocks [0, MROWS): roi; [MROWS, MROWS+6656): wT (w1 then w2 tiles).
// roi depends on selfmt (prev launch); wT only on inputs -> safe to co-run.
// LDS is a union: roi needs 31360 B, wT needs 16640 B.
__global__ __launch_bounds__(256) void roiwT_kernel(const unsigned short* __restrict__ fmT,
                                                    const float* __restrict__ rois,
                                                    unsigned short* __restrict__ A,
                                                    const float* __restrict__ w1,
                                                    unsigned short* __restrict__ w1t,
                                                    const float* __restrict__ w2,
                                                    unsigned short* __restrict__ w2t) {
  __shared__ __align__(16) char lds[31360];
  int bid = blockIdx.x;
  int t = threadIdx.x;

  if (bid < MROWS) {
    // ---------------- roi part ----------------
    unsigned short* Arow = (unsigned short*)lds;            // [12544]
    int (*sidx)[4] = (int(*)[4])(lds + 25088);              // [196][4]
    float (*swt)[4] = (float(*)[4])(lds + 28224);           // [196][4]
    int roi = bid;
    float rx1 = rois[roi * 4 + 0], ry1 = rois[roi * 4 + 1];
    float rx2 = rois[roi * 4 + 2], ry2 = rois[roi * 4 + 3];
    float roiw = fmaxf(rx2 - rx1, 1.f), roih = fmaxf(ry2 - ry1, 1.f);
    float bw = roiw * (1.f / OUTP), bh = roih * (1.f / OUTP);
    if (t < 196) {
      int oy = t / 28, rem = t % 28, ox = rem / 4, s = rem % 4, sy = s >> 1, sx = s & 1;
      float y = ry1 + ((float)oy + ((float)sy + 0.5f) * 0.5f) * bh;
      float x = rx1 + ((float)ox + ((float)sx + 0.5f) * 0.5f) * bw;
      bool valid = (y >= -1.f) && (y <= 64.f) && (x >= -1.f) && (x <= 64.f);
      float yc = fminf(fmaxf(y, 0.f), 63.f);
      float xc = fminf(fmaxf(x, 0.f), 63.f);
      int y0 = (int)floorf(yc), x0 = (int)floorf(xc);
      int y1i = min(y0 + 1, 63), x1i = min(x0 + 1, 63);
      float ly = yc - (float)y0, lx = xc - (float)x0;
      float hy = 1.f - ly, hx = 1.f - lx;
      float m = valid ? 1.f : 0.f;
      swt[t][0] = hy * hx * m;
      swt[t][1] = hy * lx * m;
      swt[t][2] = ly * hx * m;
      swt[t][3] = ly * lx * m;
      sidx[t][0] = (y0 * 64 + x0) * CCH;
      sidx[t][1] = (y0 * 64 + x1i) * CCH;
      sidx[t][2] = (y1i * 64 + x0) * CCH;
      sidx[t][3] = (y1i * 64 + x1i) * CCH;
    }
    __syncthreads();
    int b = roi / RREG;
    int cg = t & 63;                       // 4 channels: cg*4 .. cg*4+3
    int sub = t >> 6;                      // bin subset
    int start = sub * 12 + min(sub, 1);    // 0,13,25,37
    int cnt = sub == 0 ? 13 : 12;
    const unsigned short* base = fmT + (long)b * PDIM * CCH + cg * 4;
    for (int bi = 0; bi < cnt; ++bi) {
      int bin = start + bi;
      float a0 = 0.f, a1 = 0.f, a2 = 0.f, a3 = 0.f;
#pragma unroll
      for (int s = 0; s < 4; ++s) {
        int sid = bin * 4 + s;
#pragma unroll
        for (int tp = 0; tp < 4; ++tp) {
          float w = swt[sid][tp];
          ushort4v v = *(const ushort4v*)(base + sidx[sid][tp]);
          a0 += w * bf2f(v[0]);
          a1 += w * bf2f(v[1]);
          a2 += w * bf2f(v[2]);
          a3 += w * bf2f(v[3]);
        }
      }
      Arow[(cg * 4 + 0) * 49 + bin] = f2bf(a0 * 0.25f);
      Arow[(cg * 4 + 1) * 49 + bin] = f2bf(a1 * 0.25f);
      Arow[(cg * 4 + 2) * 49 + bin] = f2bf(a2 * 0.25f);
      Arow[(cg * 4 + 3) * 49 + bin] = f2bf(a3 * 0.25f);
    }
    __syncthreads();
    const ushort8v* src = (const ushort8v*)Arow;
    ushort8v* dst = (ushort8v*)(A + (long)roi * DDIM);
    for (int i = t; i < DDIM / 8; i += 256) dst[i] = src[i];
    return;
  }

  // ---------------- wT part ----------------
  float (*tile)[65] = (float(*)[65])lds;                    // [64][65]
  int wb = bid - MROWS;
  const float* in;
  unsigned short* out;
  int K, N, k0, n0;
  if (wb < (DDIM / 64) * (N1DIM / 64)) {
    in = w1; out = w1t; K = DDIM; N = N1DIM;
    k0 = (wb % (DDIM / 64)) * 64;
    n0 = (wb / (DDIM / 64)) * 64;
  } else {
    int r = wb - (DDIM / 64) * (N1DIM / 64);
    in = w2; out = w2t; K = N1DIM; N = FDIM;
    k0 = (r % (N1DIM / 64)) * 64;
    n0 = (r / (N1DIM / 64)) * 64;
  }
  int tx = t & 15, ty = t >> 4;
#pragma unroll
  for (int p = 0; p < 4; ++p) {
    int r = ty + p * 16;
    float4 v = *(const float4*)&in[(long)(k0 + r) * N + n0 + tx * 4];
    tile[r][tx * 4 + 0] = v.x;
    tile[r][tx * 4 + 1] = v.y;
    tile[r][tx * 4 + 2] = v.z;
    tile[r][tx * 4 + 3] = v.w;
  }
  __syncthreads();
#pragma unroll
  for (int p = 0; p < 4; ++p) {
    int r = ty + p * 16;
    ushort4v o;
    o[0] = f2bf(tile[tx * 4 + 0][r]);
    o[1] = f2bf(tile[tx * 4 + 1][r]);
    o[2] = f2bf(tile[tx * 4 + 2][r]);
    o[3] = f2bf(tile[tx * 4 + 3][r]);
    *(ushort4v*)&out[(long)(n0 + r) * K + k0 + tx * 4] = o;
  }
}

// ---------------- 4. split-K bf16 MFMA GEMM, counted-vmcnt pipeline ----------
__global__ __launch_bounds__(256, 2) void gemm_sk_kernel(const unsigned short* __restrict__ A,
                                                         const unsigned short* __restrict__ Bt,
                                                         float* __restrict__ Cp,
                                                         int M, int N, int K, int kchunk,
                                                         int gy, int q) {
  __shared__ unsigned short As[2 * 128 * 64];   // [buf][row][chunk^(row&7)] bf16
  __shared__ unsigned short Bs[2 * 128 * 64];
  int bid = blockIdx.x;
  int tile = (bid & 7) * q + (bid >> 3);    // bijective XCD-chunked swizzle (nwg % 8 == 0)
  int bm = tile & 7;
  int rest = tile >> 3;
  int bn = rest % gy;
  int s = rest / gy;

  int t = threadIdx.x;
  int lane = t & 63, wv = t >> 6;
  int wr = wv >> 1, wc = wv & 1;
  int fr = lane & 15, fq = lane >> 4;

  f32x4 acc[4][4];
#pragma unroll
  for (int m = 0; m < 4; ++m)
#pragma unroll
    for (int n = 0; n < 4; ++n) acc[m][n] = (f32x4){0.f, 0.f, 0.f, 0.f};

  int srow = t >> 3;
  int scol = t & 7;
  int k_begin = s * kchunk;
  int k_end = min(k_begin + kchunk, K);
  int nkt = (k_end - k_begin) >> 6;

  int garow[4], gbrow[4], schunk[4];
#pragma unroll
  for (int i = 0; i < 4; ++i) {
    int row = srow + i * 32;
    schunk[i] = (scol ^ (row & 7)) * 8;
    garow[i] = min(bm * 128 + row, M - 1);
    gbrow[i] = bn * 128 + row;
  }

#define GSTAGE(buf, kt_) do {                                                  \
    int k0_ = k_begin + (kt_) * 64;                                            \
    _Pragma("unroll")                                                          \
    for (int i = 0; i < 4; ++i)                                                \
      gload_lds16(A + (long)garow[i] * K + k0_ + schunk[i],                    \
                  (char*)As + (buf) * 16384 + t * 16 + i * 4096);              \
    _Pragma("unroll")                                                          \
    for (int i = 0; i < 4; ++i)                                                \
      gload_lds16(Bt + (long)gbrow[i] * K + k0_ + schunk[i],                   \
                  (char*)Bs + (buf) * 16384 + t * 16 + i * 4096);              \
  } while (0)

  GSTAGE(0, 0);
  GSTAGE(1, min(1, nkt - 1));

  for (int kt = 0; kt < nkt; ++kt) {
    int cur = kt & 1;
    asm volatile("s_waitcnt vmcnt(8)" ::: "memory");
    __builtin_amdgcn_sched_barrier(0);
    __builtin_amdgcn_s_barrier();
    __builtin_amdgcn_sched_barrier(0);

    const char* Ab = (const char*)As + cur * 16384;
    const char* Bb = (const char*)Bs + cur * 16384;
#pragma unroll
    for (int ks = 0; ks < 2; ++ks) {
      bf16x8 af[4], bfv[4];
#pragma unroll
      for (int m = 0; m < 4; ++m) {
        int row = wr * 64 + m * 16 + fr;
        int bc = (ks * 64 + fq * 16) ^ ((row & 7) << 4);
        af[m] = *(const bf16x8*)(Ab + row * 128 + bc);
      }
#pragma unroll
      for (int n = 0; n < 4; ++n) {
        int row = wc * 64 + n * 16 + fr;
        int bc = (ks * 64 + fq * 16) ^ ((row & 7) << 4);
        bfv[n] = *(const bf16x8*)(Bb + row * 128 + bc);
      }
#pragma unroll
      for (int m = 0; m < 4; ++m)
#pragma unroll
        for (int n = 0; n < 4; ++n)
          acc[m][n] = __builtin_amdgcn_mfma_f32_16x16x32_bf16(af[m], bfv[n], acc[m][n], 0, 0, 0);
    }

    __builtin_amdgcn_sched_barrier(0);
    __builtin_amdgcn_s_barrier();
    __builtin_amdgcn_sched_barrier(0);
    GSTAGE(cur, min(kt + 2, nkt - 1));
  }
#undef GSTAGE

  float* Cb = Cp + (long)s * M * N;
#pragma unroll
  for (int m = 0; m < 4; ++m)
#pragma unroll
    for (int n = 0; n < 4; ++n) {
      int col = bn * 128 + wc * 64 + n * 16 + fr;
#pragma unroll
      for (int j = 0; j < 4; ++j) {
        int row = bm * 128 + wr * 64 + m * 16 + fq * 4 + j;
        if (row < M) Cb[(long)row * N + col] = acc[m][n][j];
      }
    }
}

// ---------------- block reduce helper ----------------
static __device__ __forceinline__ void block_reduce2(float& a, float& b, float* sm) {
#pragma unroll
  for (int off = 32; off > 0; off >>= 1) {
    a += __shfl_down(a, off);
    b += __shfl_down(b, off);
  }
  int lane = threadIdx.x & 63, wv = threadIdx.x >> 6;
  if (lane == 0) { sm[wv] = a; sm[wv + 4] = b; }
  __syncthreads();
  a = sm[0] + sm[1] + sm[2] + sm[3];
  b = sm[4] + sm[5] + sm[6] + sm[7];
}

// ---------------- 5. partial-sum + bias + LN + ReLU -> bf16 h ----------------
__global__ __launch_bounds__(256) void ln1_kernel(const float* __restrict__ X,
                                                  const float* __restrict__ b1,
                                                  const float* __restrict__ g1,
                                                  const float* __restrict__ be1,
                                                  unsigned short* __restrict__ H) {
  __shared__ float sm[8];
  int row = blockIdx.x, t = threadIdx.x;
  float x[8];
  float sum = 0.f, sq = 0.f;
#pragma unroll
  for (int i = 0; i < 8; ++i) {
    int j = t + i * 256;
    float v = b1[j];
#pragma unroll
    for (int s = 0; s < S1; ++s) v += X[((long)s * MROWS + row) * N1DIM + j];
    x[i] = v;
    sum += v;
    sq += v * v;
  }
  block_reduce2(sum, sq, sm);
  float mu = sum * (1.f / N1DIM);
  float inv = rsqrtf(sq * (1.f / N1DIM) - mu * mu + 1e-5f);
#pragma unroll
  for (int i = 0; i < 8; ++i) {
    int j = t + i * 256;
    float y = fmaxf((x[i] - mu) * inv * g1[j] + be1[j], 0.f);
    H[(long)row * N1DIM + j] = f2bf(y);
  }
}

// ---------------- 6. partial-sum + bias + LN + missing-token -> out ----------------
__global__ __launch_bounds__(256) void ln2_kernel(const float* __restrict__ X,
                                                  const float* __restrict__ b2,
                                                  const float* __restrict__ g2,
                                                  const float* __restrict__ be2,
                                                  const float* __restrict__ miss,
                                                  const int* __restrict__ det,
                                                  float* __restrict__ out) {
  __shared__ float sm[8];
  int row = blockIdx.x, t = threadIdx.x;
  float x[3];
  float sum = 0.f, sq = 0.f;
#pragma unroll
  for (int i = 0; i < 3; ++i) {
    int j = t + i * 256;
    float v = b2[j];
#pragma unroll
    for (int s = 0; s < S2; ++s) v += X[((long)s * MROWS + row) * FDIM + j];
    x[i] = v;
    sum += v;
    sq += v * v;
  }
  block_reduce2(sum, sq, sm);
  float mu = sum * (1.f / FDIM);
  float inv = rsqrtf(sq * (1.f / FDIM) - mu * mu + 1e-5f);
  int dv = det[row];
#pragma unroll
  for (int i = 0; i < 3; ++i) {
    int j = t + i * 256;
    float y = (x[i] - mu) * inv * g2[j] + be2[j];
    out[(long)row * FDIM + j] = dv ? y : miss[j];
  }
}

extern "C" void kernel_launch(void* const* d_in, const int* in_sizes, int n_in,
                              void* d_out, int out_size, void* d_ws, size_t ws_size,
                              hipStream_t stream) {
  const float* fm     = (const float*)d_in[0];
  const float* boxes  = (const float*)d_in[1];
  const float* scores = (const float*)d_in[2];
  const int*   labels = (const int*)d_in[3];
  const float* w1     = (const float*)d_in[4];
  const float* b1     = (const float*)d_in[5];
  const float* g1     = (const float*)d_in[6];
  const float* be1    = (const float*)d_in[7];
  const float* w2     = (const float*)d_in[8];
  const float* b2     = (const float*)d_in[9];
  const float* g2     = (const float*)d_in[10];
  const float* be2    = (const float*)d_in[11];
  const float* miss   = (const float*)d_in[12];
  float* out = (float*)d_out;
  char* ws = (char*)d_ws;

  float* rois = (float*)(ws + OFF_ROIS);
  int* det = (int*)(ws + OFF_DET);
  unsigned short* Abf = (unsigned short*)(ws + OFF_A);
  unsigned short* fmT = (unsigned short*)(ws + OFF_FMT);
  unsigned short* w1t = (unsigned short*)(ws + OFF_W1T);
  unsigned short* w2t = (unsigned short*)(ws + OFF_W2T);
  float* Gp = (float*)(ws + OFF_GP);
  unsigned short* Hbf = (unsigned short*)(ws + OFF_H);

  // select (4 blocks) + fmt (8192 blocks)
  hipLaunchKernelGGL(selfmt_kernel, dim3(8192 + 4), dim3(256), 0, stream,
                     fm, fmT, boxes, scores, labels, rois, det, out + (long)MROWS * FDIM);
  // roi (928, latency-bound) packed with weight transposes (6656, BW-bound)
  hipLaunchKernelGGL(roiwT_kernel,
                     dim3(MROWS + (DDIM / 64) * (N1DIM / 64) + (N1DIM / 64) * (FDIM / 64)),
                     dim3(256), 0, stream, fmT, rois, Abf, w1, w1t, w2, w2t);
  {
    // GEMM1: 196 k-blocks; kchunk = 49*64 = 3136, exact for all 4 splits
    int nkb = DDIM / 64;
    int kc = ((nkb + S1 - 1) / S1) * 64;
    int gy = N1DIM / 128, nwg = 8 * gy * S1;          // 512 = 2 blocks/CU exactly
    hipLaunchKernelGGL(gemm_sk_kernel, dim3(nwg), dim3(256), 0, stream,
                       Abf, w1t, Gp, MROWS, N1DIM, DDIM, kc, gy, nwg / 8);
  }
  hipLaunchKernelGGL(ln1_kernel, dim3(MROWS), dim3(256), 0, stream, Gp, b1, g1, be1, Hbf);
  // W1T dead (H aliases it); G1 partials consumed -> Gp reused for GEMM2 partials
  {
    int nkb = N1DIM / 64;
    int kc = ((nkb + S2 - 1) / S2) * 64;              // 256
    int gy = FDIM / 128, nwg = 8 * gy * S2;           // 384
    hipLaunchKernelGGL(gemm_sk_kernel, dim3(nwg), dim3(256), 0, stream,
                       Hbf, w2t, Gp, MROWS, FDIM, N1DIM, kc, gy, nwg / 8);
  }
  hipLaunchKernelGGL(ln2_kernel, dim3(MROWS), dim3(256), 0, stream,
                     Gp, b2, g2, be2, miss, det, out);
}